// Round 9
// baseline (249.265 us; speedup 1.0000x reference)
//
#include <hip/hip_runtime.h>
#include <cstddef>

#define WIN 11
#define HALO 10
#define NCH 10

typedef float v2f __attribute__((ext_vector_type(2)));
typedef float v4f __attribute__((ext_vector_type(4)));

// Normalized 1D Gaussian, sigma=1.5 (constexpr: unrolled taps fold to immediates)
constexpr float Gc[WIN] = {
    0.00102838f, 0.00759876f, 0.03600077f, 0.10936069f, 0.21300554f,
    0.26601173f, 0.21300554f, 0.10936069f, 0.03600077f, 0.00759876f,
    0.00102838f};

constexpr int HPITCH = 33;        // odd pitch: spread write banks, clean reads
constexpr int RS = 76;            // ring slots; per-iter span 74 <= 76 (disjoint)
constexpr int RSZ = RS * HPITCH;  // 2508 entries

struct Ptrs {
    const float* p[5];
    const float* t[5];
};

// ---------------- shared strip-SSIM body (ring-buffer streaming) -------------
// Block = 32-wide x <=256-tall output strip; 32 output rows/iter, 1 barrier/iter.
// hq = (conv p, conv t, conv p^2, conv t^2) as float4; h4s = conv(p*t).
__device__ __forceinline__ void ssim_strip_body(
    const int lvl, const int cs, const int rsi, const int c, const Ptrs& pt,
    float* __restrict__ acc, v4f* hq, float* h4s, float* red) {
    const int H = 1024 >> lvl;
    const int Wout = H - HALO;
    const int X0 = cs * 32;
    const int strip_y0 = rsi * 256;
    const int strip_rows = min(256, Wout - strip_y0);
    const int rows_needed = strip_rows + HALO;
    const int nIter = (strip_rows + 31) >> 5;
    const float* Pc = pt.p[lvl] + (size_t)c * H * H;
    const float* Tc = pt.t[lvl] + (size_t)c * H * H;
    const int tid = threadIdx.x;
    const int r6 = tid / 6;       // S1 row within batch
    const int seg = tid - r6 * 6;
    const int x0s = seg * 6;      // h-cols x0s..x0s+5, inputs x0s..x0s+15
    const int gxb = X0 + x0s;

    auto load_row = [&](int gy, float2 lp[8], float2 lt[8]) {
        const float* Pr = Pc + (size_t)gy * H + gxb;
        const float* Tr = Tc + (size_t)gy * H + gxb;
        if (gxb + 16 <= H) {
#pragma unroll
            for (int j = 0; j < 8; ++j) {
                lp[j] = *(const float2*)(Pr + 2 * j);
                lt[j] = *(const float2*)(Tr + 2 * j);
            }
        } else {
#pragma unroll
            for (int j = 0; j < 8; ++j) {
                float2 a = make_float2(0.f, 0.f), b = make_float2(0.f, 0.f);
                if (gxb + 2 * j < H)     { a.x = Pr[2 * j];     b.x = Tr[2 * j]; }
                if (gxb + 2 * j + 1 < H) { a.y = Pr[2 * j + 1]; b.y = Tr[2 * j + 1]; }
                lp[j] = a;
                lt[j] = b;
            }
        }
    };

    auto conv_store = [&](int rr, const float2 lp[8], const float2 lt[8]) {
        v4f aq[6] = {};
        float a4[6] = {};
#pragma unroll
        for (int xi = 0; xi < 16; ++xi) {
            float pv = (xi & 1) ? lp[xi >> 1].y : lp[xi >> 1].x;
            float tv = (xi & 1) ? lt[xi >> 1].y : lt[xi >> 1].x;
            v4f xq = (v4f){pv, tv, pv * pv, tv * tv};
            float x4 = pv * tv;
#pragma unroll
            for (int o = 0; o < 6; ++o) {
                int k = xi - o;
                if (k >= 0 && k <= 10) {
                    float g = Gc[k];
                    aq[o] = aq[o] + g * xq;     // 2x v_pk_fma_f32
                    a4[o] = fmaf(g, x4, a4[o]);
                }
            }
        }
        const int sb = rr * HPITCH;
#pragma unroll
        for (int o = 0; o < 6; ++o) {
            int x = x0s + o;
            if (x < 32) {
                hq[sb + x] = aq[o];   // ds_write_b128
                h4s[sb + x] = a4[o];  // ds_write_b32
            }
        }
    };

    // Prologue: h-rows 0..41 (42 rows x 6 segs = 252 threads)
    if (tid < 252) {
        float2 lp[8], lt[8];
        load_row(strip_y0 + r6, lp, lt);
        conv_store(r6, lp, lt);
    }
    __syncthreads();

    float cs_sum = 0.f, sim_sum = 0.f;
    const int txl = tid & 31;
    const int g4 = (tid >> 5) * 4;
    int rrm = r6 + 42;
    if (rrm >= RS) rrm -= RS;  // ring row this thread's S1 writes in iter i
    int y0m = 0;               // (32*i) % RS
    for (int i = 0; i < nIter; ++i) {
        // S1 loads for NEXT window issue first (latency hides under S2)
        float2 lp[8], lt[8];
        const int hrel = 42 + 32 * i + r6;
        const bool doS1 = (tid < 192) && (i + 1 < nIter) && (hrel < rows_needed);
        if (doS1) load_row(strip_y0 + hrel, lp, lt);

        // S2: vertical conv + SSIM from resident ring rows
        {
            int sl = y0m + g4;
            if (sl >= RS) sl -= RS;
            v4f a[4] = {};
            float sA[4] = {};
#pragma unroll
            for (int yr = 0; yr < 14; ++yr) {
                int row = sl * HPITCH + txl;
                v4f vq = hq[row];     // ds_read_b128
                float v4v = h4s[row]; // ds_read_b32
#pragma unroll
                for (int o = 0; o < 4; ++o) {
                    int k = yr - o;
                    if (k >= 0 && k <= 10) {
                        float gw = Gc[k];
                        a[o] = a[o] + gw * vq;  // 2x v_pk_fma_f32
                        sA[o] = fmaf(gw, v4v, sA[o]);
                    }
                }
                ++sl;
                if (sl >= RS) sl = 0;
            }
            const float C1c = 1.0e-4f, C2c = 9.0e-4f;
            const bool colok = (X0 + txl) < Wout;
#pragma unroll
            for (int o = 0; o < 4; ++o) {
                if (colok && (32 * i + g4 + o) < strip_rows) {
                    float mu1 = a[o].x, mu2 = a[o].y;
                    float mu1s = mu1 * mu1, mu2s = mu2 * mu2, mu12 = mu1 * mu2;
                    float sig1 = a[o].z - mu1s;
                    float sig2 = a[o].w - mu2s;
                    float sig12 = sA[o] - mu12;
                    float v1 = 2.f * sig12 + C2c;
                    float v2 = sig1 + sig2 + C2c;
                    float den2 = mu1s + mu2s + C1c;
                    float num2 = 2.f * mu12 + C1c;
                    float inv = 1.f / (v2 * den2);
                    cs_sum = fmaf(v1 * den2, inv, cs_sum);
                    sim_sum = fmaf(num2 * v1, inv, sim_sum);
                }
            }
        }

        if (doS1) conv_store(rrm, lp, lt);
        rrm += 32;
        if (rrm >= RS) rrm -= RS;
        y0m += 32;
        if (y0m >= RS) y0m -= RS;
        __syncthreads();
    }

    // Block reduction + per-(lvl,ch) atomics
#pragma unroll
    for (int off = 32; off > 0; off >>= 1) {
        cs_sum += __shfl_down(cs_sum, off, 64);
        sim_sum += __shfl_down(sim_sum, off, 64);
    }
    int wave = tid >> 6;
    if ((tid & 63) == 0) {
        red[wave * 2 + 0] = sim_sum;
        red[wave * 2 + 1] = cs_sum;
    }
    __syncthreads();
    if (tid == 0) {
        float s = red[0] + red[2] + red[4] + red[6];
        float cc = red[1] + red[3] + red[5] + red[7];
        atomicAdd(&acc[(lvl * NCH + c) * 2 + 0], s);
        atomicAdd(&acc[(lvl * NCH + c) * 2 + 1], cc);
    }
}

// ---------------- pyramid pool body (64x64 lvl0 tile -> lvl1..4) -------------
__device__ __forceinline__ void pool_body(
    int pb, int ch, const float* __restrict__ P0, const float* __restrict__ T0,
    float* __restrict__ p1, float* __restrict__ t1,
    float* __restrict__ p2, float* __restrict__ t2,
    float* __restrict__ p3, float* __restrict__ t3,
    float* __restrict__ p4, float* __restrict__ t4,
    float* sp2, float* st2, float* sp3, float* st3) {
    const int tid = threadIdx.x;
    const int bx = pb & 15, by = pb >> 4;
    const int tx = tid & 15, ty = tid >> 4;

    const size_t rbase =
        ((size_t)ch * 1024 + by * 64 + ty * 4) * 1024 + bx * 64 + tx * 4;
    float4 pr[4], tr[4];
#pragma unroll
    for (int r2 = 0; r2 < 4; ++r2) {
        pr[r2] = *(const float4*)(P0 + rbase + (size_t)r2 * 1024);
        tr[r2] = *(const float4*)(T0 + rbase + (size_t)r2 * 1024);
    }
    float p1a = 0.25f * ((pr[0].x + pr[0].y) + (pr[1].x + pr[1].y));
    float p1b = 0.25f * ((pr[0].z + pr[0].w) + (pr[1].z + pr[1].w));
    float p1c = 0.25f * ((pr[2].x + pr[2].y) + (pr[3].x + pr[3].y));
    float p1d = 0.25f * ((pr[2].z + pr[2].w) + (pr[3].z + pr[3].w));
    float t1a = 0.25f * ((tr[0].x + tr[0].y) + (tr[1].x + tr[1].y));
    float t1b = 0.25f * ((tr[0].z + tr[0].w) + (tr[1].z + tr[1].w));
    float t1c = 0.25f * ((tr[2].x + tr[2].y) + (tr[3].x + tr[3].y));
    float t1d = 0.25f * ((tr[2].z + tr[2].w) + (tr[3].z + tr[3].w));
    size_t o1 = ((size_t)ch * 512 + by * 32 + ty * 2) * 512 + bx * 32 + tx * 2;
    *(float2*)(p1 + o1) = make_float2(p1a, p1b);
    *(float2*)(p1 + o1 + 512) = make_float2(p1c, p1d);
    *(float2*)(t1 + o1) = make_float2(t1a, t1b);
    *(float2*)(t1 + o1 + 512) = make_float2(t1c, t1d);
    float p2v = 0.25f * ((p1a + p1b) + (p1c + p1d));
    float t2v = 0.25f * ((t1a + t1b) + (t1c + t1d));
    size_t o2 = ((size_t)ch * 256 + by * 16 + ty) * 256 + bx * 16 + tx;
    p2[o2] = p2v;
    t2[o2] = t2v;
    sp2[tid] = p2v;
    st2[tid] = t2v;
    __syncthreads();
    if (tid < 64) {
        int x3 = tid & 7, y3 = tid >> 3;
        int i0 = (2 * y3) * 16 + 2 * x3;
        float p3v = 0.25f * ((sp2[i0] + sp2[i0 + 1]) + (sp2[i0 + 16] + sp2[i0 + 17]));
        float t3v = 0.25f * ((st2[i0] + st2[i0 + 1]) + (st2[i0 + 16] + st2[i0 + 17]));
        size_t o3 = ((size_t)ch * 128 + by * 8 + y3) * 128 + bx * 8 + x3;
        p3[o3] = p3v;
        t3[o3] = t3v;
        sp3[tid] = p3v;
        st3[tid] = t3v;
    }
    __syncthreads();
    if (tid < 16) {
        int x4 = tid & 3, y4 = tid >> 2;
        int i0 = (2 * y4) * 8 + 2 * x4;
        float p4v = 0.25f * ((sp3[i0] + sp3[i0 + 1]) + (sp3[i0 + 8] + sp3[i0 + 9]));
        float t4v = 0.25f * ((st3[i0] + st3[i0 + 1]) + (st3[i0 + 8] + st3[i0 + 9]));
        size_t o4 = ((size_t)ch * 64 + by * 4 + y4) * 64 + bx * 4 + x4;
        p4[o4] = p4v;
        t4[o4] = t4v;
    }
}

// Dispatch A: bxi<128 -> lvl0 SSIM strip (compile-time lvl=0 specialization);
// else pyramid pool block. Both independent of the pyramid outputs.
__global__ __launch_bounds__(256) void fusedA(
    Ptrs ptrs, float* __restrict__ acc,
    float* __restrict__ p1, float* __restrict__ t1,
    float* __restrict__ p2, float* __restrict__ t2,
    float* __restrict__ p3, float* __restrict__ t3,
    float* __restrict__ p4, float* __restrict__ t4) {
    __shared__ v4f hq[RSZ];     // 40128 B
    __shared__ float h4s[RSZ];  // 10032 B
    __shared__ float red[8];
    __shared__ float sp2[256], st2[256], sp3[64], st3[64];  // pool path (2.5 KB)

    const int bxi = blockIdx.x;
    const int c = blockIdx.y;
    if (bxi < 128) {
        ssim_strip_body(0, bxi & 31, bxi >> 5, c, ptrs, acc, hq, h4s, red);
    } else {
        pool_body(bxi - 128, c, ptrs.p[0], ptrs.t[0], p1, t1, p2, t2, p3, t3,
                  p4, t4, sp2, st2, sp3, st3);
    }
}

// Dispatch B: levels 1..4 strips (after pools are visible).
// Per channel: lvl1 16x2=32, lvl2 8, lvl3 4, lvl4 2 -> 46.
__global__ __launch_bounds__(256) void ssimB(Ptrs ptrs, float* __restrict__ acc) {
    __shared__ v4f hq[RSZ];
    __shared__ float h4s[RSZ];
    __shared__ float red[8];
    const int bxi = blockIdx.x;
    int lvl, cs, rsi;
    if (bxi < 32)      { lvl = 1; cs = bxi & 15; rsi = bxi >> 4; }
    else if (bxi < 40) { lvl = 2; cs = bxi - 32; rsi = 0; }
    else if (bxi < 44) { lvl = 3; cs = bxi - 40; rsi = 0; }
    else               { lvl = 4; cs = bxi - 44; rsi = 0; }
    ssim_strip_body(lvl, cs, rsi, blockIdx.y, ptrs, acc, hq, h4s, red);
}

__global__ void finalize_k(const float* __restrict__ acc, float* __restrict__ out) {
    if (threadIdx.x != 0) return;
    const double w[5] = {0.0448, 0.2856, 0.3001, 0.2363, 0.1333};
    const double counts[5] = {1014.0 * 1014.0, 502.0 * 502.0, 246.0 * 246.0,
                              118.0 * 118.0, 54.0 * 54.0};
    double total = 0.0;
    for (int c = 0; c < NCH; ++c) {
        double pc = 1.0;
        for (int l = 0; l < 4; ++l) {
            double mcs = (double)acc[(l * NCH + c) * 2 + 1] / counts[l];
            pc *= pow(mcs, w[l]);
        }
        double ms4 = (double)acc[(4 * NCH + c) * 2 + 0] / counts[4];
        double p2 = pow(ms4, w[4]);
        pc *= (p2 * p2) * (p2 * p2);  // pow2[-1] appears in all 4 product terms
        total += pc;
    }
    *out = (float)(1.0 - total);
}

extern "C" void kernel_launch(void* const* d_in, const int* in_sizes, int n_in,
                              void* d_out, int out_size, void* d_ws, size_t ws_size,
                              hipStream_t stream) {
    const float* P0 = (const float*)d_in[0];
    const float* T0 = (const float*)d_in[1];
    float* out = (float*)d_out;
    float* acc = (float*)d_ws;  // 100 used, 128 reserved

    const size_t n1 = (size_t)NCH * 512 * 512;
    const size_t n2 = (size_t)NCH * 256 * 256;
    const size_t n3 = (size_t)NCH * 128 * 128;
    const size_t n4 = (size_t)NCH * 64 * 64;
    float* p1 = acc + 128;
    float* t1 = p1 + n1;
    float* p2 = t1 + n1;
    float* t2 = p2 + n2;
    float* p3 = t2 + n2;
    float* t3 = p3 + n3;
    float* p4 = t3 + n3;
    float* t4 = p4 + n4;

    Ptrs ptrs;
    ptrs.p[0] = P0; ptrs.t[0] = T0;
    ptrs.p[1] = p1; ptrs.t[1] = t1;
    ptrs.p[2] = p2; ptrs.t[2] = t2;
    ptrs.p[3] = p3; ptrs.t[3] = t3;
    ptrs.p[4] = p4; ptrs.t[4] = t4;

    hipMemsetAsync(acc, 0, 128 * sizeof(float), stream);  // capture-safe
    fusedA<<<dim3(384, NCH, 1), 256, 0, stream>>>(ptrs, acc, p1, t1, p2, t2,
                                                  p3, t3, p4, t4);
    ssimB<<<dim3(46, NCH, 1), 256, 0, stream>>>(ptrs, acc);
    finalize_k<<<1, 64, 0, stream>>>(acc, out);
}

// Round 10
// 209.703 us; speedup vs baseline: 1.1887x; 1.1887x over previous
//
#include <hip/hip_runtime.h>
#include <cstddef>

#define WIN 11
#define HALO 10
#define NCH 10

typedef float v4f __attribute__((ext_vector_type(4)));

// Normalized 1D Gaussian, sigma=1.5 (constexpr: unrolled taps fold to immediates)
constexpr float Gc[WIN] = {
    0.00102838f, 0.00759876f, 0.03600077f, 0.10936069f, 0.21300554f,
    0.26601173f, 0.21300554f, 0.10936069f, 0.03600077f, 0.00759876f,
    0.00102838f};

constexpr int HPITCH = 33;        // odd pitch: spread write banks
constexpr int RS = 76;            // ring slots; per-iter span 74 <= 76 (disjoint)
constexpr int RSZ = RS * HPITCH;  // 2508 v4f = 39.2 KB -> 4 blocks/CU

struct Ptrs {
    const float* p[5];
    const float* t[5];
};

// ---- One-shot pyramid: 64x64 lvl0 tile -> lvl1..4, plus acc zeroing ----
__global__ __launch_bounds__(256) void pool_all(
    const float* __restrict__ P0, const float* __restrict__ T0,
    float* __restrict__ p1, float* __restrict__ t1,
    float* __restrict__ p2, float* __restrict__ t2,
    float* __restrict__ p3, float* __restrict__ t3,
    float* __restrict__ p4, float* __restrict__ t4,
    float* __restrict__ acc) {
    __shared__ float sp2[256], st2[256], sp3[64], st3[64];
    const int tid = threadIdx.x;
    if (blockIdx.x == 0 && tid < 128) acc[tid] = 0.f;

    const int b = blockIdx.x;  // 2560 = 10ch x 16 x 16
    const int bx = b & 15, by = (b >> 4) & 15, ch = b >> 8;
    const int tx = tid & 15, ty = tid >> 4;

    const size_t rbase =
        ((size_t)ch * 1024 + by * 64 + ty * 4) * 1024 + bx * 64 + tx * 4;
    float4 pr[4], tr[4];
#pragma unroll
    for (int r2 = 0; r2 < 4; ++r2) {
        pr[r2] = *(const float4*)(P0 + rbase + (size_t)r2 * 1024);
        tr[r2] = *(const float4*)(T0 + rbase + (size_t)r2 * 1024);
    }
    float p1a = 0.25f * ((pr[0].x + pr[0].y) + (pr[1].x + pr[1].y));
    float p1b = 0.25f * ((pr[0].z + pr[0].w) + (pr[1].z + pr[1].w));
    float p1c = 0.25f * ((pr[2].x + pr[2].y) + (pr[3].x + pr[3].y));
    float p1d = 0.25f * ((pr[2].z + pr[2].w) + (pr[3].z + pr[3].w));
    float t1a = 0.25f * ((tr[0].x + tr[0].y) + (tr[1].x + tr[1].y));
    float t1b = 0.25f * ((tr[0].z + tr[0].w) + (tr[1].z + tr[1].w));
    float t1c = 0.25f * ((tr[2].x + tr[2].y) + (tr[3].x + tr[3].y));
    float t1d = 0.25f * ((tr[2].z + tr[2].w) + (tr[3].z + tr[3].w));
    size_t o1 = ((size_t)ch * 512 + by * 32 + ty * 2) * 512 + bx * 32 + tx * 2;
    *(float2*)(p1 + o1) = make_float2(p1a, p1b);
    *(float2*)(p1 + o1 + 512) = make_float2(p1c, p1d);
    *(float2*)(t1 + o1) = make_float2(t1a, t1b);
    *(float2*)(t1 + o1 + 512) = make_float2(t1c, t1d);
    float p2v = 0.25f * ((p1a + p1b) + (p1c + p1d));
    float t2v = 0.25f * ((t1a + t1b) + (t1c + t1d));
    size_t o2 = ((size_t)ch * 256 + by * 16 + ty) * 256 + bx * 16 + tx;
    p2[o2] = p2v;
    t2[o2] = t2v;
    sp2[tid] = p2v;
    st2[tid] = t2v;
    __syncthreads();
    if (tid < 64) {
        int x3 = tid & 7, y3 = tid >> 3;
        int i0 = (2 * y3) * 16 + 2 * x3;
        float p3v = 0.25f * ((sp2[i0] + sp2[i0 + 1]) + (sp2[i0 + 16] + sp2[i0 + 17]));
        float t3v = 0.25f * ((st2[i0] + st2[i0 + 1]) + (st2[i0 + 16] + st2[i0 + 17]));
        size_t o3 = ((size_t)ch * 128 + by * 8 + y3) * 128 + bx * 8 + x3;
        p3[o3] = p3v;
        t3[o3] = t3v;
        sp3[tid] = p3v;
        st3[tid] = t3v;
    }
    __syncthreads();
    if (tid < 16) {
        int x4 = tid & 3, y4 = tid >> 2;
        int i0 = (2 * y4) * 8 + 2 * x4;
        float p4v = 0.25f * ((sp3[i0] + sp3[i0 + 1]) + (sp3[i0 + 8] + sp3[i0 + 9]));
        float t4v = 0.25f * ((st3[i0] + st3[i0 + 1]) + (st3[i0 + 8] + st3[i0 + 9]));
        size_t o4 = ((size_t)ch * 64 + by * 4 + y4) * 64 + bx * 4 + x4;
        p4[o4] = p4v;
        t4[o4] = t4v;
    }
}

// Column-strip streaming SSIM, 4-channel ring (p, t, p^2+t^2, p*t).
// Block = 32-wide x <=256-tall strip; 32 output rows/iter; 1 barrier/iter.
// Per-channel blocks: lvl0 32x4=128, lvl1 16x2=32, lvl2 8, lvl3 4, lvl4 2 = 174.
__global__ __launch_bounds__(256) void ssim_strip(Ptrs ptrs,
                                                  float* __restrict__ acc) {
    __shared__ v4f hq[RSZ];  // 40128 B -> 4 blocks/CU
    __shared__ float red[8];

    const int bxi = blockIdx.x;  // 0..173
    int lvl, base;
    if (bxi < 128)      { lvl = 0; base = 0; }
    else if (bxi < 160) { lvl = 1; base = 128; }
    else if (bxi < 168) { lvl = 2; base = 160; }
    else if (bxi < 172) { lvl = 3; base = 168; }
    else                { lvl = 4; base = 172; }
    const int local = bxi - base;
    const int H = 1024 >> lvl;
    const int Wout = H - HALO;
    const int ncol = 32 >> lvl;
    const int cs = local & (ncol - 1);
    const int rsi = local >> (5 - lvl);
    const int X0 = cs * 32;
    const int strip_y0 = rsi * 256;
    const int strip_rows = min(256, Wout - strip_y0);
    const int rows_needed = strip_rows + HALO;
    const int nIter = (strip_rows + 31) >> 5;

    const int c = blockIdx.y;
    const float* Pc = ptrs.p[lvl] + (size_t)c * H * H;
    const float* Tc = ptrs.t[lvl] + (size_t)c * H * H;
    const int tid = threadIdx.x;
    const int r6 = tid / 6;       // S1 row within batch
    const int seg = tid - r6 * 6;
    const int x0s = seg * 6;      // h-cols x0s..x0s+5, inputs x0s..x0s+15
    const int gxb = X0 + x0s;

    auto load_row = [&](int gy, float2 lp[8], float2 lt[8]) {
        const float* Pr = Pc + (size_t)gy * H + gxb;
        const float* Tr = Tc + (size_t)gy * H + gxb;
        if (gxb + 16 <= H) {
#pragma unroll
            for (int j = 0; j < 8; ++j) {
                lp[j] = *(const float2*)(Pr + 2 * j);
                lt[j] = *(const float2*)(Tr + 2 * j);
            }
        } else {
#pragma unroll
            for (int j = 0; j < 8; ++j) {
                float2 a = make_float2(0.f, 0.f), b = make_float2(0.f, 0.f);
                if (gxb + 2 * j < H)     { a.x = Pr[2 * j];     b.x = Tr[2 * j]; }
                if (gxb + 2 * j + 1 < H) { a.y = Pr[2 * j + 1]; b.y = Tr[2 * j + 1]; }
                lp[j] = a;
                lt[j] = b;
            }
        }
    };

    // horizontal conv of one row -> ring slot rr; 2 pk_fma per tap
    auto conv_store = [&](int rr, const float2 lp[8], const float2 lt[8]) {
        v4f aq[6] = {};
#pragma unroll
        for (int xi = 0; xi < 16; ++xi) {
            float pv = (xi & 1) ? lp[xi >> 1].y : lp[xi >> 1].x;
            float tv = (xi & 1) ? lt[xi >> 1].y : lt[xi >> 1].x;
            float pp = pv * pv, tt = tv * tv;
            v4f xq = (v4f){pv, tv, pp + tt, pv * tv};
#pragma unroll
            for (int o = 0; o < 6; ++o) {
                int k = xi - o;
                if (k >= 0 && k <= 10) {
                    aq[o] = aq[o] + Gc[k] * xq;  // 2x v_pk_fma_f32
                }
            }
        }
        const int sb = rr * HPITCH;
#pragma unroll
        for (int o = 0; o < 6; ++o) {
            int x = x0s + o;
            if (x < 32) hq[sb + x] = aq[o];  // ds_write_b128
        }
    };

    // Prologue: h-rows 0..41 (42 rows x 6 segs = 252 threads)
    if (tid < 252) {
        float2 lp[8], lt[8];
        load_row(strip_y0 + r6, lp, lt);
        conv_store(r6, lp, lt);
    }
    __syncthreads();

    float cs_sum = 0.f, sim_sum = 0.f;
    const int txl = tid & 31;
    const int g4 = (tid >> 5) * 4;
    int rrm = r6 + 42;
    if (rrm >= RS) rrm -= RS;
    int y0m = 0;  // (32*i) % RS
    for (int i = 0; i < nIter; ++i) {
        // S1 loads for NEXT window issue first (latency hides under S2)
        float2 lp[8], lt[8];
        const int hrel = 42 + 32 * i + r6;
        const bool doS1 = (tid < 192) && (i + 1 < nIter) && (hrel < rows_needed);
        if (doS1) load_row(strip_y0 + hrel, lp, lt);

        // S2: vertical conv + SSIM from resident ring rows
        {
            int sl = y0m + g4;
            if (sl >= RS) sl -= RS;
            v4f a[4] = {};
#pragma unroll
            for (int yr = 0; yr < 14; ++yr) {
                v4f vq = hq[sl * HPITCH + txl];  // ds_read_b128
#pragma unroll
                for (int o = 0; o < 4; ++o) {
                    int k = yr - o;
                    if (k >= 0 && k <= 10) {
                        a[o] = a[o] + Gc[k] * vq;  // 2x v_pk_fma_f32
                    }
                }
                ++sl;
                if (sl >= RS) sl = 0;
            }
            const float C1c = 1.0e-4f, C2c = 9.0e-4f;
            const bool colok = (X0 + txl) < Wout;
#pragma unroll
            for (int o = 0; o < 4; ++o) {
                if (colok && (32 * i + g4 + o) < strip_rows) {
                    float mu1 = a[o].x, mu2 = a[o].y;
                    float mu1s = mu1 * mu1, mu2s = mu2 * mu2, mu12 = mu1 * mu2;
                    // v2 = conv(p^2+t^2) - mu1^2 - mu2^2 + C2
                    float v2 = a[o].z - mu1s - mu2s + C2c;
                    float v1 = 2.f * (a[o].w - mu12) + C2c;
                    float den2 = mu1s + mu2s + C1c;
                    float num2 = 2.f * mu12 + C1c;
                    float inv = 1.f / (v2 * den2);
                    cs_sum = fmaf(v1 * den2, inv, cs_sum);
                    sim_sum = fmaf(num2 * v1, inv, sim_sum);
                }
            }
        }

        if (doS1) conv_store(rrm, lp, lt);
        rrm += 32;
        if (rrm >= RS) rrm -= RS;
        y0m += 32;
        if (y0m >= RS) y0m -= RS;
        __syncthreads();
    }

    // Block reduction + per-(lvl,ch) atomics
#pragma unroll
    for (int off = 32; off > 0; off >>= 1) {
        cs_sum += __shfl_down(cs_sum, off, 64);
        sim_sum += __shfl_down(sim_sum, off, 64);
    }
    int wave = tid >> 6;
    if ((tid & 63) == 0) {
        red[wave * 2 + 0] = sim_sum;
        red[wave * 2 + 1] = cs_sum;
    }
    __syncthreads();
    if (tid == 0) {
        float s = red[0] + red[2] + red[4] + red[6];
        float cc = red[1] + red[3] + red[5] + red[7];
        atomicAdd(&acc[(lvl * NCH + c) * 2 + 0], s);
        atomicAdd(&acc[(lvl * NCH + c) * 2 + 1], cc);
    }
}

__global__ void finalize_k(const float* __restrict__ acc, float* __restrict__ out) {
    if (threadIdx.x != 0) return;
    const double w[5] = {0.0448, 0.2856, 0.3001, 0.2363, 0.1333};
    const double counts[5] = {1014.0 * 1014.0, 502.0 * 502.0, 246.0 * 246.0,
                              118.0 * 118.0, 54.0 * 54.0};
    double total = 0.0;
    for (int c = 0; c < NCH; ++c) {
        double pc = 1.0;
        for (int l = 0; l < 4; ++l) {
            double mcs = (double)acc[(l * NCH + c) * 2 + 1] / counts[l];
            pc *= pow(mcs, w[l]);
        }
        double ms4 = (double)acc[(4 * NCH + c) * 2 + 0] / counts[4];
        double p2 = pow(ms4, w[4]);
        pc *= (p2 * p2) * (p2 * p2);  // pow2[-1] appears in all 4 product terms
        total += pc;
    }
    *out = (float)(1.0 - total);
}

extern "C" void kernel_launch(void* const* d_in, const int* in_sizes, int n_in,
                              void* d_out, int out_size, void* d_ws, size_t ws_size,
                              hipStream_t stream) {
    const float* P0 = (const float*)d_in[0];
    const float* T0 = (const float*)d_in[1];
    float* out = (float*)d_out;
    float* acc = (float*)d_ws;  // 100 used, 128 reserved

    const size_t n1 = (size_t)NCH * 512 * 512;
    const size_t n2 = (size_t)NCH * 256 * 256;
    const size_t n3 = (size_t)NCH * 128 * 128;
    const size_t n4 = (size_t)NCH * 64 * 64;
    float* p1 = acc + 128;
    float* t1 = p1 + n1;
    float* p2 = t1 + n1;
    float* t2 = p2 + n2;
    float* p3 = t2 + n2;
    float* t3 = p3 + n3;
    float* p4 = t3 + n3;
    float* t4 = p4 + n4;

    pool_all<<<2560, 256, 0, stream>>>(P0, T0, p1, t1, p2, t2, p3, t3, p4, t4, acc);

    Ptrs ptrs;
    ptrs.p[0] = P0; ptrs.t[0] = T0;
    ptrs.p[1] = p1; ptrs.t[1] = t1;
    ptrs.p[2] = p2; ptrs.t[2] = t2;
    ptrs.p[3] = p3; ptrs.t[3] = t3;
    ptrs.p[4] = p4; ptrs.t[4] = t4;

    ssim_strip<<<dim3(174, NCH, 1), 256, 0, stream>>>(ptrs, acc);

    finalize_k<<<1, 64, 0, stream>>>(acc, out);
}

// Round 11
// 200.557 us; speedup vs baseline: 1.2429x; 1.0456x over previous
//
#include <hip/hip_runtime.h>
#include <cstddef>

#define WIN 11
#define HALO 10
#define NCH 10

typedef float v4f __attribute__((ext_vector_type(4)));

// Normalized 1D Gaussian, sigma=1.5 (constexpr: unrolled taps fold to immediates)
constexpr float Gc[WIN] = {
    0.00102838f, 0.00759876f, 0.03600077f, 0.10936069f, 0.21300554f,
    0.26601173f, 0.21300554f, 0.10936069f, 0.03600077f, 0.00759876f,
    0.00102838f};

constexpr int HPITCH = 33;        // odd pitch: spread write banks
constexpr int RS = 76;            // ring slots; per-iter span 74 <= 76 (disjoint)
constexpr int RSZ = RS * HPITCH;  // 2508 v4f = 39.2 KB -> 4 blocks/CU

struct Ptrs {
    const float* p[5];
    const float* t[5];
};

// ---- One-shot pyramid: 64x64 lvl0 tile -> lvl1..4, plus acc zeroing ----
// (~110 MB in ~15us ~= 7 TB/s: at the HBM/L3 roofline — do not touch)
__global__ __launch_bounds__(256) void pool_all(
    const float* __restrict__ P0, const float* __restrict__ T0,
    float* __restrict__ p1, float* __restrict__ t1,
    float* __restrict__ p2, float* __restrict__ t2,
    float* __restrict__ p3, float* __restrict__ t3,
    float* __restrict__ p4, float* __restrict__ t4,
    float* __restrict__ acc) {
    __shared__ float sp2[256], st2[256], sp3[64], st3[64];
    const int tid = threadIdx.x;
    if (blockIdx.x == 0 && tid < 128) acc[tid] = 0.f;

    const int b = blockIdx.x;  // 2560 = 10ch x 16 x 16
    const int bx = b & 15, by = (b >> 4) & 15, ch = b >> 8;
    const int tx = tid & 15, ty = tid >> 4;

    const size_t rbase =
        ((size_t)ch * 1024 + by * 64 + ty * 4) * 1024 + bx * 64 + tx * 4;
    float4 pr[4], tr[4];
#pragma unroll
    for (int r2 = 0; r2 < 4; ++r2) {
        pr[r2] = *(const float4*)(P0 + rbase + (size_t)r2 * 1024);
        tr[r2] = *(const float4*)(T0 + rbase + (size_t)r2 * 1024);
    }
    float p1a = 0.25f * ((pr[0].x + pr[0].y) + (pr[1].x + pr[1].y));
    float p1b = 0.25f * ((pr[0].z + pr[0].w) + (pr[1].z + pr[1].w));
    float p1c = 0.25f * ((pr[2].x + pr[2].y) + (pr[3].x + pr[3].y));
    float p1d = 0.25f * ((pr[2].z + pr[2].w) + (pr[3].z + pr[3].w));
    float t1a = 0.25f * ((tr[0].x + tr[0].y) + (tr[1].x + tr[1].y));
    float t1b = 0.25f * ((tr[0].z + tr[0].w) + (tr[1].z + tr[1].w));
    float t1c = 0.25f * ((tr[2].x + tr[2].y) + (tr[3].x + tr[3].y));
    float t1d = 0.25f * ((tr[2].z + tr[2].w) + (tr[3].z + tr[3].w));
    size_t o1 = ((size_t)ch * 512 + by * 32 + ty * 2) * 512 + bx * 32 + tx * 2;
    *(float2*)(p1 + o1) = make_float2(p1a, p1b);
    *(float2*)(p1 + o1 + 512) = make_float2(p1c, p1d);
    *(float2*)(t1 + o1) = make_float2(t1a, t1b);
    *(float2*)(t1 + o1 + 512) = make_float2(t1c, t1d);
    float p2v = 0.25f * ((p1a + p1b) + (p1c + p1d));
    float t2v = 0.25f * ((t1a + t1b) + (t1c + t1d));
    size_t o2 = ((size_t)ch * 256 + by * 16 + ty) * 256 + bx * 16 + tx;
    p2[o2] = p2v;
    t2[o2] = t2v;
    sp2[tid] = p2v;
    st2[tid] = t2v;
    __syncthreads();
    if (tid < 64) {
        int x3 = tid & 7, y3 = tid >> 3;
        int i0 = (2 * y3) * 16 + 2 * x3;
        float p3v = 0.25f * ((sp2[i0] + sp2[i0 + 1]) + (sp2[i0 + 16] + sp2[i0 + 17]));
        float t3v = 0.25f * ((st2[i0] + st2[i0 + 1]) + (st2[i0 + 16] + st2[i0 + 17]));
        size_t o3 = ((size_t)ch * 128 + by * 8 + y3) * 128 + bx * 8 + x3;
        p3[o3] = p3v;
        t3[o3] = t3v;
        sp3[tid] = p3v;
        st3[tid] = t3v;
    }
    __syncthreads();
    if (tid < 16) {
        int x4 = tid & 3, y4 = tid >> 2;
        int i0 = (2 * y4) * 8 + 2 * x4;
        float p4v = 0.25f * ((sp3[i0] + sp3[i0 + 1]) + (sp3[i0 + 8] + sp3[i0 + 9]));
        float t4v = 0.25f * ((st3[i0] + st3[i0 + 1]) + (st3[i0 + 8] + st3[i0 + 9]));
        size_t o4 = ((size_t)ch * 64 + by * 4 + y4) * 64 + bx * 4 + x4;
        p4[o4] = p4v;
        t4[o4] = t4v;
    }
}

// Column-strip streaming SSIM, 4-channel ring (p, t, p^2+t^2, p*t).
// Wave-specialized: waves 0-1 (tid<128) = S2 consumers (8 outputs/thread,
// 18 ds_read_b128 per 8 outputs); waves 2-3 = S1 producers (8-col segs from
// 18 inputs, single-buffer software pipeline: conv batch i, then issue batch
// i+1 loads -> latency spans the barrier + next S2 phase).
// Per-channel blocks: lvl0 32x4=128, lvl1 16x2=32, lvl2 8, lvl3 4, lvl4 2 = 174.
__global__ __launch_bounds__(256) void ssim_strip(Ptrs ptrs,
                                                  float* __restrict__ acc) {
    __shared__ v4f hq[RSZ];  // 40128 B -> 4 blocks/CU
    __shared__ float red[8];

    const int bxi = blockIdx.x;  // 0..173
    int lvl, base;
    if (bxi < 128)      { lvl = 0; base = 0; }
    else if (bxi < 160) { lvl = 1; base = 128; }
    else if (bxi < 168) { lvl = 2; base = 160; }
    else if (bxi < 172) { lvl = 3; base = 168; }
    else                { lvl = 4; base = 172; }
    const int local = bxi - base;
    const int H = 1024 >> lvl;
    const int Wout = H - HALO;
    const int ncol = 32 >> lvl;
    const int cs = local & (ncol - 1);
    const int rsi = local >> (5 - lvl);
    const int X0 = cs * 32;
    const int strip_y0 = rsi * 256;
    const int strip_rows = min(256, Wout - strip_y0);
    const int rows_needed = strip_rows + HALO;
    const int nIter = (strip_rows + 31) >> 5;

    const int c = blockIdx.y;
    const float* Pc = ptrs.p[lvl] + (size_t)c * H * H;
    const float* Tc = ptrs.t[lvl] + (size_t)c * H * H;
    const int tid = threadIdx.x;

    // load 18 cols (9 float2) of row gy at col base gxb
    auto load_row18 = [&](int gy, int gxb, float2 lp[9], float2 lt[9]) {
        const float* Pr = Pc + (size_t)gy * H + gxb;
        const float* Tr = Tc + (size_t)gy * H + gxb;
        if (gxb + 18 <= H) {
#pragma unroll
            for (int j = 0; j < 9; ++j) {
                lp[j] = *(const float2*)(Pr + 2 * j);
                lt[j] = *(const float2*)(Tr + 2 * j);
            }
        } else {
#pragma unroll
            for (int j = 0; j < 9; ++j) {
                float2 a = make_float2(0.f, 0.f), b = make_float2(0.f, 0.f);
                if (gxb + 2 * j < H)     { a.x = Pr[2 * j];     b.x = Tr[2 * j]; }
                if (gxb + 2 * j + 1 < H) { a.y = Pr[2 * j + 1]; b.y = Tr[2 * j + 1]; }
                lp[j] = a;
                lt[j] = b;
            }
        }
    };

    // horizontal conv: 8 outputs (cols x0..x0+7) from 18 inputs -> ring slot rr
    auto conv_store8 = [&](int rr, int x0, const float2 lp[9], const float2 lt[9]) {
        v4f aq[8] = {};
#pragma unroll
        for (int xi = 0; xi < 18; ++xi) {
            float pv = (xi & 1) ? lp[xi >> 1].y : lp[xi >> 1].x;
            float tv = (xi & 1) ? lt[xi >> 1].y : lt[xi >> 1].x;
            v4f xq = (v4f){pv, tv, pv * pv + tv * tv, pv * tv};
#pragma unroll
            for (int o = 0; o < 8; ++o) {
                int k = xi - o;
                if (k >= 0 && k <= 10) aq[o] = aq[o] + Gc[k] * xq;  // 2x pk_fma
            }
        }
        const int sb = rr * HPITCH + x0;
#pragma unroll
        for (int o = 0; o < 8; ++o) hq[sb + o] = aq[o];  // ds_write_b128
    };

    // ---- Prologue: h-rows 0..41 via 42 rows x 4 segs (168 threads) ----
    {
        const int r = tid >> 2, seg = tid & 3;
        if (r < 42) {
            float2 lp[9], lt[9];
            load_row18(strip_y0 + r, X0 + 8 * seg, lp, lt);
            conv_store8(r, 8 * seg, lp, lt);
        }
    }

    // ---- Producer preload of batch 0 (rows 42..73) ----
    const bool isProd = (tid >= 128);
    const int pr = tid & 31;          // producer row in batch
    const int pseg = (tid >> 5) & 3;  // producer 8-col segment
    float2 plp[9], plt[9];
    int prRow = 42 + pr;              // absolute h-row of current loaded batch
    int prSlot = prRow;               // ring slot (42+pr < 76)
    bool pHave = false;
    if (isProd && prRow < rows_needed && nIter > 1) {
        load_row18(strip_y0 + prRow, X0 + 8 * pseg, plp, plt);
        pHave = true;
    }
    __syncthreads();

    // ---- Main loop: 32 output rows/iter, 1 barrier/iter ----
    float cs_sum = 0.f, sim_sum = 0.f;
    const int txl = tid & 31;
    const int g = (tid >> 5) & 3;  // consumer band (tid<128): rows 8g..8g+7
    int y0m = 0;                   // (32*i) % RS
    for (int i = 0; i < nIter; ++i) {
        if (isProd) {
            // store batch i (loaded last iter), then issue batch i+1 loads
            if (pHave) conv_store8(prSlot, 8 * pseg, plp, plt);
            prSlot += 32;
            if (prSlot >= RS) prSlot -= RS;
            prRow += 32;
            pHave = (prRow < rows_needed) && (i + 2 < nIter + 1) && (i + 1 < nIter);
            if (pHave) load_row18(strip_y0 + prRow, X0 + 8 * pseg, plp, plt);
        } else {
            // S2: 8 outputs over 18 resident ring rows
            int sl = y0m + 8 * g;
            if (sl >= RS) sl -= RS;
            v4f a[8] = {};
#pragma unroll
            for (int yr = 0; yr < 18; ++yr) {
                v4f vq = hq[sl * HPITCH + txl];  // ds_read_b128
#pragma unroll
                for (int o = 0; o < 8; ++o) {
                    int k = yr - o;
                    if (k >= 0 && k <= 10) a[o] = a[o] + Gc[k] * vq;  // 2x pk_fma
                }
                ++sl;
                if (sl >= RS) sl = 0;
            }
            const float C1c = 1.0e-4f, C2c = 9.0e-4f;
            const bool colok = (X0 + txl) < Wout;
            const int orow0 = 32 * i + 8 * g;
#pragma unroll
            for (int o = 0; o < 8; ++o) {
                if (colok && (orow0 + o) < strip_rows) {
                    float mu1 = a[o].x, mu2 = a[o].y;
                    float mu1s = mu1 * mu1, mu2s = mu2 * mu2, mu12 = mu1 * mu2;
                    float v2 = a[o].z - mu1s - mu2s + C2c;
                    float v1 = 2.f * (a[o].w - mu12) + C2c;
                    float den2 = mu1s + mu2s + C1c;
                    float num2 = 2.f * mu12 + C1c;
                    float inv = 1.f / (v2 * den2);
                    cs_sum = fmaf(v1 * den2, inv, cs_sum);
                    sim_sum = fmaf(num2 * v1, inv, sim_sum);
                }
            }
        }
        y0m += 32;
        if (y0m >= RS) y0m -= RS;
        __syncthreads();
    }

    // ---- Block reduction (producers contribute zeros) ----
#pragma unroll
    for (int off = 32; off > 0; off >>= 1) {
        cs_sum += __shfl_down(cs_sum, off, 64);
        sim_sum += __shfl_down(sim_sum, off, 64);
    }
    int wave = tid >> 6;
    if ((tid & 63) == 0) {
        red[wave * 2 + 0] = sim_sum;
        red[wave * 2 + 1] = cs_sum;
    }
    __syncthreads();
    if (tid == 0) {
        float s = red[0] + red[2] + red[4] + red[6];
        float cc = red[1] + red[3] + red[5] + red[7];
        atomicAdd(&acc[(lvl * NCH + c) * 2 + 0], s);
        atomicAdd(&acc[(lvl * NCH + c) * 2 + 1], cc);
    }
}

__global__ void finalize_k(const float* __restrict__ acc, float* __restrict__ out) {
    if (threadIdx.x != 0) return;
    const double w[5] = {0.0448, 0.2856, 0.3001, 0.2363, 0.1333};
    const double counts[5] = {1014.0 * 1014.0, 502.0 * 502.0, 246.0 * 246.0,
                              118.0 * 118.0, 54.0 * 54.0};
    double total = 0.0;
    for (int c = 0; c < NCH; ++c) {
        double pc = 1.0;
        for (int l = 0; l < 4; ++l) {
            double mcs = (double)acc[(l * NCH + c) * 2 + 1] / counts[l];
            pc *= pow(mcs, w[l]);
        }
        double ms4 = (double)acc[(4 * NCH + c) * 2 + 0] / counts[4];
        double p2 = pow(ms4, w[4]);
        pc *= (p2 * p2) * (p2 * p2);  // pow2[-1] appears in all 4 product terms
        total += pc;
    }
    *out = (float)(1.0 - total);
}

extern "C" void kernel_launch(void* const* d_in, const int* in_sizes, int n_in,
                              void* d_out, int out_size, void* d_ws, size_t ws_size,
                              hipStream_t stream) {
    const float* P0 = (const float*)d_in[0];
    const float* T0 = (const float*)d_in[1];
    float* out = (float*)d_out;
    float* acc = (float*)d_ws;  // 100 used, 128 reserved

    const size_t n1 = (size_t)NCH * 512 * 512;
    const size_t n2 = (size_t)NCH * 256 * 256;
    const size_t n3 = (size_t)NCH * 128 * 128;
    const size_t n4 = (size_t)NCH * 64 * 64;
    float* p1 = acc + 128;
    float* t1 = p1 + n1;
    float* p2 = t1 + n1;
    float* t2 = p2 + n2;
    float* p3 = t2 + n2;
    float* t3 = p3 + n3;
    float* p4 = t3 + n3;
    float* t4 = p4 + n4;

    pool_all<<<2560, 256, 0, stream>>>(P0, T0, p1, t1, p2, t2, p3, t3, p4, t4, acc);

    Ptrs ptrs;
    ptrs.p[0] = P0; ptrs.t[0] = T0;
    ptrs.p[1] = p1; ptrs.t[1] = t1;
    ptrs.p[2] = p2; ptrs.t[2] = t2;
    ptrs.p[3] = p3; ptrs.t[3] = t3;
    ptrs.p[4] = p4; ptrs.t[4] = t4;

    ssim_strip<<<dim3(174, NCH, 1), 256, 0, stream>>>(ptrs, acc);

    finalize_k<<<1, 64, 0, stream>>>(acc, out);
}